// Round 2
// baseline (1596.726 us; speedup 1.0000x reference)
//
#include <hip/hip_runtime.h>
#include <hip/hip_bf16.h>
#include <math.h>

#define NNODES 50000
#define NEDGES 800000
#define RDIM   300
#define KPAD   320            // K padded to multiple of 32 for MFMA
#define LDA    328            // LDS row stride (bf16 elems) for rbf tile: 656 B, 16B-aligned
#define LDW    72             // LDS row stride for w1 tile: 144 B, 16B-aligned

typedef __attribute__((ext_vector_type(8))) short short8;
typedef __attribute__((ext_vector_type(4))) float floatx4;

__device__ __forceinline__ float ssp(float x) {
    // softplus(x) - ln2, numerically stable
    return fmaxf(x, 0.0f) + log1pf(expf(-fabsf(x))) - 0.69314718056f;
}

__device__ __forceinline__ unsigned short f2bf(float f) {
    unsigned int u = __float_as_uint(f);
    unsigned int r = (u + 0x7FFFu + ((u >> 16) & 1u)) >> 16;   // RNE
    return (unsigned short)r;
}

// ---------------- prep: transpose weights to bf16 [n][k] layouts ----------------
__global__ void prep_weights(const float* __restrict__ fw1, const float* __restrict__ fw2,
                             unsigned short* __restrict__ fw1t, unsigned short* __restrict__ fw2t) {
    int t = threadIdx.x + blockIdx.x * blockDim.x;
    int stride = blockDim.x * gridDim.x;
    for (int idx = t; idx < 64 * KPAD; idx += stride) {
        int n = idx / KPAD, k = idx - n * KPAD;
        float v = (k < RDIM) ? fw1[k * 64 + n] : 0.0f;
        fw1t[idx] = f2bf(v);
    }
    for (int idx = t; idx < 64 * 64; idx += stride) {
        int n = idx >> 6, k = idx & 63;
        fw2t[idx] = f2bf(fw2[k * 64 + n]);
    }
}

// ---------------- h = x @ l1w + l1b ----------------
__global__ __launch_bounds__(256) void linear1_kernel(const float* __restrict__ x,
    const float* __restrict__ w, const float* __restrict__ b, float* __restrict__ h) {
    __shared__ float xs[64][65];
    __shared__ float ws[64][65];
    int t = threadIdx.x;
    int r0 = blockIdx.x * 64;
    for (int i = t; i < 4096; i += 256) ws[i >> 6][i & 63] = w[i];
    for (int i = t; i < 4096; i += 256) {
        int r = i >> 6;
        xs[r][i & 63] = (r0 + r < NNODES) ? x[(size_t)(r0 + r) * 64 + (i & 63)] : 0.0f;
    }
    __syncthreads();
    int c = t & 63;
    int rb = t >> 6;
    float bias = b[c];
    #pragma unroll 4
    for (int ri = 0; ri < 16; ri++) {
        int r = rb * 16 + ri;
        float acc = bias;
        #pragma unroll
        for (int k = 0; k < 64; k++) acc += xs[r][k] * ws[k][c];
        if (r0 + r < NNODES) h[(size_t)(r0 + r) * 64 + c] = acc;
    }
}

// ---------------- edge kernel: filter-gen GEMMs + cutoff + gather/scatter ----------------
__global__ __launch_bounds__(256) void edge_kernel(
    const int* __restrict__ ei,                // [2][E] int32 (harness converts int64 -> int32)
    const float* __restrict__ rbf,             // [E][300]
    const float* __restrict__ dist,            // [E]
    const float* __restrict__ cutoffp,         // [1]
    const unsigned short* __restrict__ fw1t,   // [64][320] bf16
    const float* __restrict__ fb1,             // [64]
    const unsigned short* __restrict__ fw2t,   // [64][64] bf16
    const float* __restrict__ fb2,             // [64]
    const float* __restrict__ h,               // [N][64]
    float* __restrict__ agg)                   // [N][64] (d_out, zeroed)
{
    __shared__ __align__(16) unsigned short rbf_s[64 * LDA];
    __shared__ __align__(16) unsigned short w1_s[64 * LDW];
    __shared__ float cut_s[64];
    __shared__ int src_s[64], dst_s[64];

    const int t = threadIdx.x;
    const int e0 = blockIdx.x * 64;
    const int lane = t & 63;
    const int wv = t >> 6;                 // wave 0..3: owns n-cols [16*wv, 16*wv+16)

    // edge metadata
    if (t < 64) {
        int e = e0 + t;
        dst_s[t] = ei[e];                  // edge_index[0] : scatter destination
        src_s[t] = ei[NEDGES + e];         // edge_index[1] : gather source
        float co = *cutoffp;
        cut_s[t] = 1.0f + cosf(3.14159265f * dist[e] / co);
    }

    // register-resident B fragments (per wave's n-tile) + biases
    const int n = (wv << 4) + (lane & 15);
    const int kb = (lane >> 4) << 3;
    short8 b1[10];
    #pragma unroll
    for (int ks = 0; ks < 10; ks++)
        b1[ks] = *(const short8*)&fw1t[n * KPAD + ks * 32 + kb];
    short8 b2[2];
    #pragma unroll
    for (int ks = 0; ks < 2; ks++)
        b2[ks] = *(const short8*)&fw2t[n * 64 + ks * 32 + kb];
    const float fb1n = fb1[n];
    const float fb2n = fb2[n];

    // stage rbf tile -> LDS bf16.  Tile is 64 rows x 300 f32 = 4800 float4, contiguous.
    {
        const float4* rp = (const float4*)(rbf + (size_t)e0 * RDIM);
        #pragma unroll
        for (int i = 0; i < 19; i++) {
            int idx4 = t + 256 * i;
            if (idx4 < 4800) {
                float4 v = rp[idx4];
                int row = idx4 / 75;          // 75 float4 per row (300 floats)
                int col4 = idx4 - row * 75;
                unsigned long long packed =
                    (unsigned long long)f2bf(v.x)
                  | ((unsigned long long)f2bf(v.y) << 16)
                  | ((unsigned long long)f2bf(v.z) << 32)
                  | ((unsigned long long)f2bf(v.w) << 48);
                *(unsigned long long*)&rbf_s[row * LDA + col4 * 4] = packed;
            }
        }
        if (t < 64) {  // zero-pad k = 300..319
            #pragma unroll
            for (int c4 = 75; c4 < 80; c4++)
                *(unsigned long long*)&rbf_s[t * LDA + c4 * 4] = 0ULL;
        }
    }
    __syncthreads();

    // GEMM1: W1[64 edges][16 n] per wave = ssp(rbf @ fw1 + fb1)
    const floatx4 zero4 = {0.0f, 0.0f, 0.0f, 0.0f};
    floatx4 acc[4] = {zero4, zero4, zero4, zero4};
    const int arow = lane & 15;
    #pragma unroll
    for (int ks = 0; ks < 10; ks++) {
        #pragma unroll
        for (int mt = 0; mt < 4; mt++) {
            short8 a = *(const short8*)&rbf_s[(mt * 16 + arow) * LDA + ks * 32 + kb];
            acc[mt] = __builtin_amdgcn_mfma_f32_16x16x32_bf16(a, b1[ks], acc[mt], 0, 0, 0);
        }
    }

    // bias + ssp, write W1 to LDS in bf16 (A-layout source for GEMM2)
    #pragma unroll
    for (int mt = 0; mt < 4; mt++) {
        #pragma unroll
        for (int r = 0; r < 4; r++) {
            int edge = mt * 16 + ((lane >> 4) << 2) + r;
            float v = ssp(acc[mt][r] + fb1n);
            w1_s[edge * LDW + n] = f2bf(v);
        }
    }
    __syncthreads();

    // GEMM2: W2 = ssp(W1 @ fw2 + fb2)
    floatx4 acc2[4] = {zero4, zero4, zero4, zero4};
    #pragma unroll
    for (int ks = 0; ks < 2; ks++) {
        #pragma unroll
        for (int mt = 0; mt < 4; mt++) {
            short8 a = *(const short8*)&w1_s[(mt * 16 + arow) * LDW + ks * 32 + kb];
            acc2[mt] = __builtin_amdgcn_mfma_f32_16x16x32_bf16(a, b2[ks], acc2[mt], 0, 0, 0);
        }
    }

    // epilogue: cutoff * ssp(.) ; msg = w * h[src]; scatter-add to agg[dst]
    #pragma unroll
    for (int mt = 0; mt < 4; mt++) {
        #pragma unroll
        for (int r = 0; r < 4; r++) {
            int el = mt * 16 + ((lane >> 4) << 2) + r;
            float w2v = ssp(acc2[mt][r] + fb2n) * cut_s[el];
            float msg = w2v * h[(size_t)src_s[el] * 64 + n];
            atomicAdd(&agg[(size_t)dst_s[el] * 64 + n], msg);
        }
    }
}

// ---------------- out = ssp(agg@l2w+l2b)@l3w + l3b + x0, in-place on d_out ----------------
__global__ __launch_bounds__(256) void output_kernel(float* __restrict__ out,
    const float* __restrict__ x0,
    const float* __restrict__ l2w, const float* __restrict__ l2b,
    const float* __restrict__ l3w, const float* __restrict__ l3b) {
    __shared__ float as[64][65];
    __shared__ float w2s[64][65];
    __shared__ float w3s[64][65];
    __shared__ float ts[64][65];
    int t = threadIdx.x;
    int r0 = blockIdx.x * 64;
    for (int i = t; i < 4096; i += 256) w2s[i >> 6][i & 63] = l2w[i];
    for (int i = t; i < 4096; i += 256) w3s[i >> 6][i & 63] = l3w[i];
    for (int i = t; i < 4096; i += 256) {
        int r = i >> 6;
        as[r][i & 63] = (r0 + r < NNODES) ? out[(size_t)(r0 + r) * 64 + (i & 63)] : 0.0f;
    }
    __syncthreads();
    int c = t & 63;
    int rb = t >> 6;
    float b2 = l2b[c];
    #pragma unroll 4
    for (int ri = 0; ri < 16; ri++) {
        int r = rb * 16 + ri;
        float acc = b2;
        #pragma unroll
        for (int k = 0; k < 64; k++) acc += as[r][k] * w2s[k][c];
        ts[r][c] = ssp(acc);
    }
    __syncthreads();
    float b3 = l3b[c];
    #pragma unroll 4
    for (int ri = 0; ri < 16; ri++) {
        int r = rb * 16 + ri;
        float acc = b3;
        #pragma unroll
        for (int k = 0; k < 64; k++) acc += ts[r][k] * w3s[k][c];
        if (r0 + r < NNODES)
            out[(size_t)(r0 + r) * 64 + c] = acc + x0[(size_t)(r0 + r) * 64 + c];
    }
}

extern "C" void kernel_launch(void* const* d_in, const int* in_sizes, int n_in,
                              void* d_out, int out_size, void* d_ws, size_t ws_size,
                              hipStream_t stream) {
    const int* ei              = (const int*)d_in[0];     // int inputs arrive as int32
    const float* node_feature  = (const float*)d_in[1];
    const float* rbf           = (const float*)d_in[2];
    const float* dist          = (const float*)d_in[3];
    const float* cutoff        = (const float*)d_in[4];
    const float* fw1           = (const float*)d_in[5];
    const float* fb1           = (const float*)d_in[6];
    const float* fw2           = (const float*)d_in[7];
    const float* fb2           = (const float*)d_in[8];
    const float* l1w           = (const float*)d_in[9];
    const float* l1b           = (const float*)d_in[10];
    const float* l2w           = (const float*)d_in[11];
    const float* l2b           = (const float*)d_in[12];
    const float* l3w           = (const float*)d_in[13];
    const float* l3b           = (const float*)d_in[14];

    // workspace layout: small weight buffers first, then h
    unsigned short* fw1t = (unsigned short*)d_ws;                       // 64*320*2 = 40960 B
    unsigned short* fw2t = (unsigned short*)((char*)d_ws + 40960);      // 64*64*2  =  8192 B
    float* h = (float*)((char*)d_ws + 49152);                           // 50000*64*4 = 12.8 MB
    float* agg = (float*)d_out;

    hipMemsetAsync(d_out, 0, (size_t)out_size * sizeof(float), stream);
    prep_weights<<<64, 256, 0, stream>>>(fw1, fw2, fw1t, fw2t);
    linear1_kernel<<<(NNODES + 63) / 64, 256, 0, stream>>>(node_feature, l1w, l1b, h);
    edge_kernel<<<NEDGES / 64, 256, 0, stream>>>(ei, rbf, dist, cutoff, fw1t, fb1, fw2t, fb2, h, agg);
    output_kernel<<<(NNODES + 63) / 64, 256, 0, stream>>>(agg, node_feature, l2w, l2b, l3w, l3b);
}